// Round 20
// baseline (74.640 us; speedup 1.0000x reference)
//
#include <hip/hip_runtime.h>
#include <hip/hip_bf16.h>

typedef __attribute__((ext_vector_type(4))) float f32x4;
typedef __attribute__((ext_vector_type(2))) float f32x2;
typedef __attribute__((ext_vector_type(8))) short bf16x8;

#define HW    16384   // 128*128
#define CDIM  256
#define BOFF  16384   // B region base in LDS (A: [0,16384))

__device__ __forceinline__ unsigned short f2bf(float x) {
    union { float f; unsigned u; } c; c.f = x;
    unsigned r = c.u + 0x7fffu + ((c.u >> 16) & 1u);   // RNE
    return (unsigned short)(r >> 16);
}

// Tile layout (R2-proven): rows of 64 k bf16 = 128 B,
// byte(row,k) = row*128 + ((k*2) ^ ((row&7)<<4)).
__device__ __forceinline__ int tswz(int row, int kbyte) {
    return row * 128 + (kbyte ^ ((row & 7) << 4));
}

// Prep: write W1 as 8 x 16KB chunks, each the exact byte image of one
// (n_half, kk) B-tile in LDS (bf16 + tswz). 8192 threads, 8 k each.
__global__ __launch_bounds__(256) void w1_prep(
    const float* __restrict__ W1, char* __restrict__ w1p) {
    const int t  = blockIdx.x * 256 + threadIdx.x;   // 0..8191
    const int cg = t >> 5;            // global channel 0..255
    const int k0 = (t & 31) << 3;     // 0..248, 8 k per thread
    const int nh = cg >> 7;
    const int cl = cg & 127;
    const int kk = k0 >> 6;
    const int kl = k0 & 63;
    const float* wp = W1 + (size_t)cg * CDIM + k0;
    const float4 u = *reinterpret_cast<const float4*>(wp);
    const float4 v = *reinterpret_cast<const float4*>(wp + 4);
    bf16x8 w;
    w[0] = (short)f2bf(u.x); w[1] = (short)f2bf(u.y);
    w[2] = (short)f2bf(u.z); w[3] = (short)f2bf(u.w);
    w[4] = (short)f2bf(v.x); w[5] = (short)f2bf(v.y);
    w[6] = (short)f2bf(v.z); w[7] = (short)f2bf(v.w);
    *reinterpret_cast<bf16x8*>(
        w1p + (size_t)(nh * 4 + kk) * 16384 + tswz(cl, kl * 2)) = w;
}

// F2t[px][c] = sum_k W1[c,k] * feat[k][px]  (FP8 E4M3, channel-last).
// R18 base + B staged via global_load_lds from the pre-swizzled W1_prep
// (T21 pattern: linear LDS dest + pre-swizzled global source). Deletes
// per K-step/thread: 8 float4 loads + 32 cvt + 4 ds_writes + bv[32] regs.
// B double-buffered (LDS 48KB); arrival covered by the pre-barrier vmcnt
// drain. Kept verbatim: tswz, depth-2 A reg prefetch (R12 -4us), XCD map
// (R9 -8us), (256,2) (arg>=3 spills R6/R10), fp8 epilogue (R18).
__global__ __launch_bounds__(256, 2) void f2_gemm(
    const float* __restrict__ feat, const char* __restrict__ w1p,
    unsigned char* __restrict__ f2t) {
    __shared__ short lds[24576];            // 48KB: A 16KB + B dbuf 2x16KB
    char* const ldsc = (char*)lds;

    const int t      = threadIdx.x;
    const int b      = blockIdx.x;
    const int m_tile = ((b & 7) << 7) | (b >> 4);   // xcd*128 + j
    const int n_half = (b >> 3) & 1;
    const int m_base = m_tile << 7;
    const float* fb  = feat + (size_t)(m_base >> 14) * CDIM * HW + (m_base & (HW - 1));

    const int lane = t & 63;
    const int wid  = t >> 6;
    const int wm   = wid >> 1;           // 2 px-slabs of 64
    const int wn   = wid & 1;            // 2 c-slabs of 64
    const int rr   = lane & 15;
    const int kg   = lane >> 4;

    const int sm0 = (t >> 3) << 2;       // A staging row base 0..124
    const int kb  = (t & 7) << 3;        // A staging k base 0..56

    f32x4 acc[4][4] = {};                // [mi(px)][ni(c)] -> D[c][px]
    float av[2][8][4];                   // A raw, double reg buffer

    auto load_a = [&](int kk, int rb) {
        const float* fk = fb + (size_t)(kk * 64 + kb) * HW + sm0;
#pragma unroll
        for (int dk = 0; dk < 8; ++dk) {
            const float4 v = *reinterpret_cast<const float4*>(fk + (size_t)dk * HW);
            av[rb][dk][0] = v.x; av[rb][dk][1] = v.y;
            av[rb][dk][2] = v.z; av[rb][dk][3] = v.w;
        }
    };
    // B: linear 16KB copy, global -> LDS, no VGPR round-trip.
    auto glds_b = [&](int kk, int bbuf) {
        const char* src = w1p + (size_t)(n_half * 4 + kk) * 16384
                        + wid * 4096 + (lane << 4);
        char* dst = ldsc + BOFF + bbuf * 16384 + wid * 4096;  // wave-uniform
#pragma unroll
        for (int i = 0; i < 4; ++i)
            __builtin_amdgcn_global_load_lds(
                (const void*)(src + i * 1024), (void*)(dst + i * 1024), 16, 0, 0);
    };

    auto write_a = [&](int rb) {
#pragma unroll
        for (int dm = 0; dm < 4; ++dm) {           // transpose in regs
            const int row = sm0 + dm;
            bf16x8 w;
#pragma unroll
            for (int dk = 0; dk < 8; ++dk) w[dk] = (short)f2bf(av[rb][dk][dm]);
            *reinterpret_cast<bf16x8*>(ldsc + tswz(row, kb * 2)) = w;
        }
    };

    auto compute = [&](int bbuf) {
        const char* bbase = ldsc + BOFF + bbuf * 16384;
#pragma unroll
        for (int ks = 0; ks < 2; ++ks) {
            const int kb2 = ks * 64 + (kg << 4);
            bf16x8 af[4], bfr[4];
#pragma unroll
            for (int mi = 0; mi < 4; ++mi) {
                const int row = wm * 64 + mi * 16 + rr;
                af[mi] = *reinterpret_cast<const bf16x8*>(ldsc + tswz(row, kb2));
            }
#pragma unroll
            for (int ni = 0; ni < 4; ++ni) {
                const int c = wn * 64 + ni * 16 + rr;
                bfr[ni] = *reinterpret_cast<const bf16x8*>(bbase + tswz(c, kb2));
            }
#pragma unroll
            for (int mi = 0; mi < 4; ++mi)
#pragma unroll
                for (int ni = 0; ni < 4; ++ni)
                    acc[mi][ni] = __builtin_amdgcn_mfma_f32_16x16x32_bf16(
                        bfr[ni], af[mi], acc[mi][ni], 0, 0, 0);   // D[c][px]
        }
    };

    // prologue: A(0),A(1) reg-loads in flight; B(0) -> LDS buf0; write A(0)
    load_a(0, 0);
    load_a(1, 1);
    glds_b(0, 0);
    write_a(0);
    __syncthreads();   // implicit vmcnt(0) drains glds_b(0)

    // main loop: A(k+2) regs + B(k+1)->buf^1 issued over compute(k)
#pragma unroll
    for (int kk = 0; kk < 4; ++kk) {
        if (kk + 2 < 4) load_a(kk + 2, kk & 1);
        if (kk + 1 < 4) glds_b(kk + 1, (kk + 1) & 1);
        compute(kk & 1);
        __syncthreads();
        if (kk < 3) { write_a((kk + 1) & 1); __syncthreads(); }
    }

    // epilogue: lane has 4 consecutive c at fixed px -> fp8 pack -> 4B store
#pragma unroll
    for (int mi = 0; mi < 4; ++mi) {
        const int px = m_base + wm * 64 + mi * 16 + rr;
#pragma unroll
        for (int ni = 0; ni < 4; ++ni) {
            const int c0 = n_half * 128 + wn * 64 + ni * 16 + kg * 4;
            int p = __builtin_amdgcn_cvt_pk_fp8_f32(
                acc[mi][ni][0], acc[mi][ni][1], 0, false);
            p = __builtin_amdgcn_cvt_pk_fp8_f32(
                acc[mi][ni][2], acc[mi][ni][3], p, true);
            *reinterpret_cast<unsigned*>(f2t + (size_t)px * CDIM + c0) = (unsigned)p;
        }
    }
}

// 2 sample points per wave: 32 lanes/point, 8 channels/lane (one uint2 = 8 fp8
// per corner). Bilinear-weighted sum, relu(s+b1).W2, 5-step shfl_xor reduce.
__global__ __launch_bounds__(256) void point_kernel(
    const unsigned char* __restrict__ f2t,
    const float* __restrict__ be,
    const float* __restrict__ b1, const float* __restrict__ W2,
    float* __restrict__ out) {
    const int wave = (blockIdx.x << 2) | ((threadIdx.x >> 6) & 3);
    const int lane = threadIdx.x & 63;
    const int p    = (wave << 1) | (lane >> 5);     // 0..65535
    const int l5   = lane & 31;
    const int c0   = l5 << 3;

    const float ex = be[p * 2 + 0];
    const float ey = be[p * 2 + 1];
    const float gx = ex * (2.0f / 128.0f) - 1.0f;
    const float gy = ey * (2.0f / 128.0f) - 1.0f;
    const float px = (gx + 1.0f) * 64.0f - 0.5f;
    const float py = (gy + 1.0f) * 64.0f - 0.5f;
    const float x0f = floorf(px), y0f = floorf(py);
    const int   x0 = (int)x0f, y0 = (int)y0f;
    const float wx1 = px - x0f, wy1 = py - y0f;
    const float wx0 = 1.0f - wx1, wy0 = 1.0f - wy1;

    const size_t pix_base = (size_t)(p >> 13) * HW;

    float s[8] = {};
#pragma unroll
    for (int cy = 0; cy < 2; ++cy) {
        const int   yi  = y0 + cy;
        const float wy  = cy ? wy1 : wy0;
        const bool  yin = (yi >= 0) && (yi < 128);
        const int   yc  = min(max(yi, 0), 127);
#pragma unroll
        for (int cx = 0; cx < 2; ++cx) {
            const int   xi  = x0 + cx;
            const float wx  = cx ? wx1 : wx0;
            const bool  xin = (xi >= 0) && (xi < 128);
            const int   xc  = min(max(xi, 0), 127);
            const float w   = wx * wy * (float)(xin && yin);
            const uint2 v = *reinterpret_cast<const uint2*>(
                &f2t[(pix_base + (size_t)yc * 128 + xc) * 256 + c0]);
            const f32x2 f01 = __builtin_amdgcn_cvt_pk_f32_fp8((int)v.x, false);
            const f32x2 f23 = __builtin_amdgcn_cvt_pk_f32_fp8((int)v.x, true);
            const f32x2 f45 = __builtin_amdgcn_cvt_pk_f32_fp8((int)v.y, false);
            const f32x2 f67 = __builtin_amdgcn_cvt_pk_f32_fp8((int)v.y, true);
            s[0] += w * f01[0]; s[1] += w * f01[1];
            s[2] += w * f23[0]; s[3] += w * f23[1];
            s[4] += w * f45[0]; s[5] += w * f45[1];
            s[6] += w * f67[0]; s[7] += w * f67[1];
        }
    }
    const float4 bb0 = *reinterpret_cast<const float4*>(&b1[c0]);
    const float4 bb1 = *reinterpret_cast<const float4*>(&b1[c0 + 4]);
    const float4 wa0 = *reinterpret_cast<const float4*>(&W2[c0]);
    const float4 wa1 = *reinterpret_cast<const float4*>(&W2[c0 + 4]);
    const float4 wb0 = *reinterpret_cast<const float4*>(&W2[256 + c0]);
    const float4 wb1 = *reinterpret_cast<const float4*>(&W2[256 + c0 + 4]);
    float bias[8] = {bb0.x, bb0.y, bb0.z, bb0.w, bb1.x, bb1.y, bb1.z, bb1.w};
    float w2a[8]  = {wa0.x, wa0.y, wa0.z, wa0.w, wa1.x, wa1.y, wa1.z, wa1.w};
    float w2b[8]  = {wb0.x, wb0.y, wb0.z, wb0.w, wb1.x, wb1.y, wb1.z, wb1.w};

    float a0 = 0.f, a1 = 0.f;
#pragma unroll
    for (int j = 0; j < 8; ++j) {
        const float h = fmaxf(s[j] + bias[j], 0.f);
        a0 += h * w2a[j];
        a1 += h * w2b[j];
    }
#pragma unroll
    for (int off = 16; off > 0; off >>= 1) {
        a0 += __shfl_xor(a0, off);
        a1 += __shfl_xor(a1, off);
    }
    if (l5 == 0) {
        out[p * 2 + 0] = ex + a0;
        out[p * 2 + 1] = ey + a1;
    }
}

extern "C" void kernel_launch(void* const* d_in, const int* in_sizes, int n_in,
                              void* d_out, int out_size, void* d_ws, size_t ws_size,
                              hipStream_t stream) {
    const float* feat = (const float*)d_in[0];
    const float* be   = (const float*)d_in[1];
    const float* W1   = (const float*)d_in[2];
    const float* b1   = (const float*)d_in[3];
    const float* W2   = (const float*)d_in[4];
    float* out = (float*)d_out;
    unsigned char* f2t = (unsigned char*)d_ws;              // 32 MiB fp8
    char* w1p = (char*)d_ws + (33554432);                   // 128 KiB prep

    w1_prep<<<32, 256, 0, stream>>>(W1, w1p);
    f2_gemm<<<2048, 256, 0, stream>>>(feat, w1p, f2t);
    point_kernel<<<8192, 256, 0, stream>>>(f2t, be, b1, W2, out);
}

// Round 21
// 71.600 us; speedup vs baseline: 1.0425x; 1.0425x over previous
//
#include <hip/hip_runtime.h>
#include <hip/hip_bf16.h>

typedef __attribute__((ext_vector_type(4))) float f32x4;
typedef __attribute__((ext_vector_type(2))) float f32x2;
typedef __attribute__((ext_vector_type(8))) short bf16x8;

#define HW    16384   // 128*128
#define CDIM  256
#define BOFF  16384   // B region base in LDS (A: [0,16384)); B: 4 x 16KB chunks

__device__ __forceinline__ unsigned short f2bf(float x) {
    union { float f; unsigned u; } c; c.f = x;
    unsigned r = c.u + 0x7fffu + ((c.u >> 16) & 1u);   // RNE
    return (unsigned short)(r >> 16);
}

// Tile layout (R2-proven): rows of 64 k bf16 = 128 B,
// byte(row,k) = row*128 + ((k*2) ^ ((row&7)<<4)).
__device__ __forceinline__ int tswz(int row, int kbyte) {
    return row * 128 + (kbyte ^ ((row & 7) << 4));
}

// Prep: write W1 as 8 x 16KB chunks, each the exact byte image of one
// (n_half, kk) B-tile in LDS (bf16 + tswz). 8192 threads, 8 k each.
__global__ __launch_bounds__(256) void w1_prep(
    const float* __restrict__ W1, char* __restrict__ w1p) {
    const int t  = blockIdx.x * 256 + threadIdx.x;   // 0..8191
    const int cg = t >> 5;            // global channel 0..255
    const int k0 = (t & 31) << 3;     // 0..248, 8 k per thread
    const int nh = cg >> 7;
    const int cl = cg & 127;
    const int kk = k0 >> 6;
    const int kl = k0 & 63;
    const float* wp = W1 + (size_t)cg * CDIM + k0;
    const float4 u = *reinterpret_cast<const float4*>(wp);
    const float4 v = *reinterpret_cast<const float4*>(wp + 4);
    bf16x8 w;
    w[0] = (short)f2bf(u.x); w[1] = (short)f2bf(u.y);
    w[2] = (short)f2bf(u.z); w[3] = (short)f2bf(u.w);
    w[4] = (short)f2bf(v.x); w[5] = (short)f2bf(v.y);
    w[6] = (short)f2bf(v.z); w[7] = (short)f2bf(v.w);
    *reinterpret_cast<bf16x8*>(
        w1p + (size_t)(nh * 4 + kk) * 16384 + tswz(cl, kl * 2)) = w;
}

// F2t[px][c] = sum_k W1[c,k] * feat[k][px]  (FP8 E4M3, channel-last).
// R20 champion (74.6us) + TWO m-tiles per block with B FULLY LDS-RESIDENT:
//   - all 4 B K-chunks (64KB) staged ONCE per block via global_load_lds from
//     the pre-swizzled W1_prep (L2-resident source) -> zero B work in loop
//   - grid 1024: b -> xcd=b&7, n_half=(b>>3)&1, jj=b>>4; tiles 2jj,2jj+1
//     (same XCD, same image; n_half siblings still 8 apart -> R9 property)
//   - per-CU block generations 8 -> 4 (half the exposed prologue chains)
//   - steady loop: champion's exact A-path (depth-2 reg prefetch, 2-barrier
//     step); mid-kernel fp8 epilogue for tile0 (global stores, no LDS hazard)
// Spill audit vs R14: bv[32] gone (glds), av 64 + misc ~84 VGPR + 64 AGPR --
// same as R20's measured 84. All reg-buffer indices static under unroll.
__global__ __launch_bounds__(256, 2) void f2_gemm(
    const float* __restrict__ feat, const char* __restrict__ w1p,
    unsigned char* __restrict__ f2t) {
    __shared__ __attribute__((aligned(16))) char ldsc[81920];  // A 16KB + B 64KB

    const int t      = threadIdx.x;
    const int b      = blockIdx.x;                  // 0..1023
    const int xcd    = b & 7;
    const int n_half = (b >> 3) & 1;
    const int jj     = b >> 4;                      // 0..63
    const int mt0    = xcd * 128 + jj * 2;          // tile0; tile1 = +1
    const int m_base0 = mt0 << 7;
    const float* fb[2];
    fb[0] = feat + (size_t)(m_base0 >> 14) * (CDIM * HW) + (m_base0 & (HW - 1));
    fb[1] = fb[0] + 128;                            // same image, +128 px

    const int lane = t & 63;
    const int wid  = t >> 6;
    const int wm   = wid >> 1;           // 2 px-slabs of 64
    const int wn   = wid & 1;            // 2 c-slabs of 64
    const int rr   = lane & 15;
    const int kg   = lane >> 4;

    const int sm0 = (t >> 3) << 2;       // A staging row base 0..124
    const int kb  = (t & 7) << 3;        // A staging k base 0..56

    f32x4 acc[4][4] = {};                // [mi(px)][ni(c)] -> D[c][px]
    float av[2][8][4];                   // A raw, double reg buffer

    auto load_a = [&](const float* fbase, int kk, int rb) {
        const float* fk = fbase + (size_t)(kk * 64 + kb) * HW + sm0;
#pragma unroll
        for (int dk = 0; dk < 8; ++dk) {
            const float4 v = *reinterpret_cast<const float4*>(fk + (size_t)dk * HW);
            av[rb][dk][0] = v.x; av[rb][dk][1] = v.y;
            av[rb][dk][2] = v.z; av[rb][dk][3] = v.w;
        }
    };

    auto write_a = [&](int rb) {
#pragma unroll
        for (int dm = 0; dm < 4; ++dm) {           // transpose in regs
            const int row = sm0 + dm;
            bf16x8 w;
#pragma unroll
            for (int dk = 0; dk < 8; ++dk) w[dk] = (short)f2bf(av[rb][dk][dm]);
            *reinterpret_cast<bf16x8*>(ldsc + tswz(row, kb * 2)) = w;
        }
    };

    auto compute = [&](int kk) {
        const char* bbase = ldsc + BOFF + kk * 16384;
#pragma unroll
        for (int ks = 0; ks < 2; ++ks) {
            const int kb2 = ks * 64 + (kg << 4);
            bf16x8 af[4], bfr[4];
#pragma unroll
            for (int mi = 0; mi < 4; ++mi) {
                const int row = wm * 64 + mi * 16 + rr;
                af[mi] = *reinterpret_cast<const bf16x8*>(ldsc + tswz(row, kb2));
            }
#pragma unroll
            for (int ni = 0; ni < 4; ++ni) {
                const int c = wn * 64 + ni * 16 + rr;
                bfr[ni] = *reinterpret_cast<const bf16x8*>(bbase + tswz(c, kb2));
            }
#pragma unroll
            for (int mi = 0; mi < 4; ++mi)
#pragma unroll
                for (int ni = 0; ni < 4; ++ni)
                    acc[mi][ni] = __builtin_amdgcn_mfma_f32_16x16x32_bf16(
                        bfr[ni], af[mi], acc[mi][ni], 0, 0, 0);   // D[c][px]
        }
    };

    auto store_acc = [&](int tile) {     // fp8 pack -> 4B stores; then rezero
        const int mb = m_base0 + tile * 128;
#pragma unroll
        for (int mi = 0; mi < 4; ++mi) {
            const int px = mb + wm * 64 + mi * 16 + rr;
#pragma unroll
            for (int ni = 0; ni < 4; ++ni) {
                const int c0 = n_half * 128 + wn * 64 + ni * 16 + kg * 4;
                int p = __builtin_amdgcn_cvt_pk_fp8_f32(
                    acc[mi][ni][0], acc[mi][ni][1], 0, false);
                p = __builtin_amdgcn_cvt_pk_fp8_f32(
                    acc[mi][ni][2], acc[mi][ni][3], p, true);
                *reinterpret_cast<unsigned*>(f2t + (size_t)px * CDIM + c0) = (unsigned)p;
                acc[mi][ni] = f32x4{0.f, 0.f, 0.f, 0.f};
            }
        }
    };

    // ---- prologue: ALL 4 B-chunks -> LDS once; A(0),A(1) of tile0 in regs
    {
        const char* src = w1p + (size_t)n_half * 65536 + wid * 4096 + (lane << 4);
        char* dst = ldsc + BOFF + wid * 4096;      // wave-uniform base
#pragma unroll
        for (int kk = 0; kk < 4; ++kk)
#pragma unroll
            for (int i = 0; i < 4; ++i)
                __builtin_amdgcn_global_load_lds(
                    (const void*)(src + kk * 16384 + i * 1024),
                    (void*)(dst + kk * 16384 + i * 1024), 16, 0, 0);
    }
    load_a(fb[0], 0, 0);
    load_a(fb[0], 1, 1);
    write_a(0);
    __syncthreads();   // drains glds B chunks + orders A write

    // ---- main: 8 steps = 2 tiles x 4 K-chunks; only A staged per step ----
#pragma unroll
    for (int tile = 0; tile < 2; ++tile) {
#pragma unroll
        for (int kk = 0; kk < 4; ++kk) {
            const int s = tile * 4 + kk;
            if (s + 2 < 8)                        // depth-2 A prefetch
                load_a(fb[(s + 2) >> 2], (s + 2) & 3, (s + 2) & 1);
            compute(kk);
            if (kk == 3) store_acc(tile);         // mid/final epilogue
            __syncthreads();
            if (s < 7) { write_a((s + 1) & 1); __syncthreads(); }
        }
    }
}

// 2 sample points per wave: 32 lanes/point, 8 channels/lane (one uint2 = 8 fp8
// per corner). Bilinear-weighted sum, relu(s+b1).W2, 5-step shfl_xor reduce.
__global__ __launch_bounds__(256) void point_kernel(
    const unsigned char* __restrict__ f2t,
    const float* __restrict__ be,
    const float* __restrict__ b1, const float* __restrict__ W2,
    float* __restrict__ out) {
    const int wave = (blockIdx.x << 2) | ((threadIdx.x >> 6) & 3);
    const int lane = threadIdx.x & 63;
    const int p    = (wave << 1) | (lane >> 5);     // 0..65535
    const int l5   = lane & 31;
    const int c0   = l5 << 3;

    const float ex = be[p * 2 + 0];
    const float ey = be[p * 2 + 1];
    const float gx = ex * (2.0f / 128.0f) - 1.0f;
    const float gy = ey * (2.0f / 128.0f) - 1.0f;
    const float px = (gx + 1.0f) * 64.0f - 0.5f;
    const float py = (gy + 1.0f) * 64.0f - 0.5f;
    const float x0f = floorf(px), y0f = floorf(py);
    const int   x0 = (int)x0f, y0 = (int)y0f;
    const float wx1 = px - x0f, wy1 = py - y0f;
    const float wx0 = 1.0f - wx1, wy0 = 1.0f - wy1;

    const size_t pix_base = (size_t)(p >> 13) * HW;

    float s[8] = {};
#pragma unroll
    for (int cy = 0; cy < 2; ++cy) {
        const int   yi  = y0 + cy;
        const float wy  = cy ? wy1 : wy0;
        const bool  yin = (yi >= 0) && (yi < 128);
        const int   yc  = min(max(yi, 0), 127);
#pragma unroll
        for (int cx = 0; cx < 2; ++cx) {
            const int   xi  = x0 + cx;
            const float wx  = cx ? wx1 : wx0;
            const bool  xin = (xi >= 0) && (xi < 128);
            const int   xc  = min(max(xi, 0), 127);
            const float w   = wx * wy * (float)(xin && yin);
            const uint2 v = *reinterpret_cast<const uint2*>(
                &f2t[(pix_base + (size_t)yc * 128 + xc) * 256 + c0]);
            const f32x2 f01 = __builtin_amdgcn_cvt_pk_f32_fp8((int)v.x, false);
            const f32x2 f23 = __builtin_amdgcn_cvt_pk_f32_fp8((int)v.x, true);
            const f32x2 f45 = __builtin_amdgcn_cvt_pk_f32_fp8((int)v.y, false);
            const f32x2 f67 = __builtin_amdgcn_cvt_pk_f32_fp8((int)v.y, true);
            s[0] += w * f01[0]; s[1] += w * f01[1];
            s[2] += w * f23[0]; s[3] += w * f23[1];
            s[4] += w * f45[0]; s[5] += w * f45[1];
            s[6] += w * f67[0]; s[7] += w * f67[1];
        }
    }
    const float4 bb0 = *reinterpret_cast<const float4*>(&b1[c0]);
    const float4 bb1 = *reinterpret_cast<const float4*>(&b1[c0 + 4]);
    const float4 wa0 = *reinterpret_cast<const float4*>(&W2[c0]);
    const float4 wa1 = *reinterpret_cast<const float4*>(&W2[c0 + 4]);
    const float4 wb0 = *reinterpret_cast<const float4*>(&W2[256 + c0]);
    const float4 wb1 = *reinterpret_cast<const float4*>(&W2[256 + c0 + 4]);
    float bias[8] = {bb0.x, bb0.y, bb0.z, bb0.w, bb1.x, bb1.y, bb1.z, bb1.w};
    float w2a[8]  = {wa0.x, wa0.y, wa0.z, wa0.w, wa1.x, wa1.y, wa1.z, wa1.w};
    float w2b[8]  = {wb0.x, wb0.y, wb0.z, wb0.w, wb1.x, wb1.y, wb1.z, wb1.w};

    float a0 = 0.f, a1 = 0.f;
#pragma unroll
    for (int j = 0; j < 8; ++j) {
        const float h = fmaxf(s[j] + bias[j], 0.f);
        a0 += h * w2a[j];
        a1 += h * w2b[j];
    }
#pragma unroll
    for (int off = 16; off > 0; off >>= 1) {
        a0 += __shfl_xor(a0, off);
        a1 += __shfl_xor(a1, off);
    }
    if (l5 == 0) {
        out[p * 2 + 0] = ex + a0;
        out[p * 2 + 1] = ey + a1;
    }
}

extern "C" void kernel_launch(void* const* d_in, const int* in_sizes, int n_in,
                              void* d_out, int out_size, void* d_ws, size_t ws_size,
                              hipStream_t stream) {
    const float* feat = (const float*)d_in[0];
    const float* be   = (const float*)d_in[1];
    const float* W1   = (const float*)d_in[2];
    const float* b1   = (const float*)d_in[3];
    const float* W2   = (const float*)d_in[4];
    float* out = (float*)d_out;
    unsigned char* f2t = (unsigned char*)d_ws;              // 32 MiB fp8
    char* w1p = (char*)d_ws + (33554432);                   // 128 KiB prep

    w1_prep<<<32, 256, 0, stream>>>(W1, w1p);
    f2_gemm<<<1024, 256, 0, stream>>>(feat, w1p, f2t);
    point_kernel<<<8192, 256, 0, stream>>>(f2t, be, b1, W2, out);
}

// Round 22
// 71.074 us; speedup vs baseline: 1.0502x; 1.0074x over previous
//
#include <hip/hip_runtime.h>
#include <hip/hip_bf16.h>

typedef __attribute__((ext_vector_type(4))) float f32x4;
typedef __attribute__((ext_vector_type(2))) float f32x2;
typedef __attribute__((ext_vector_type(8))) short bf16x8;

#define HW    16384   // 128*128
#define CDIM  256
#define BOFF  16384   // B region base in LDS (A: [0,16384)); B: 4 x 16KB chunks

__device__ __forceinline__ unsigned short f2bf(float x) {
    union { float f; unsigned u; } c; c.f = x;
    unsigned r = c.u + 0x7fffu + ((c.u >> 16) & 1u);   // RNE
    return (unsigned short)(r >> 16);
}

// Tile layout (R2-proven): rows of 64 k bf16 = 128 B,
// byte(row,k) = row*128 + ((k*2) ^ ((row&7)<<4)).
__device__ __forceinline__ int tswz(int row, int kbyte) {
    return row * 128 + (kbyte ^ ((row & 7) << 4));
}

// Prep: write W1 as 8 x 16KB chunks, each the exact byte image of one
// (n_half, kk) B-tile in LDS (bf16 + tswz). 8192 threads, 8 k each.
__global__ __launch_bounds__(256) void w1_prep(
    const float* __restrict__ W1, char* __restrict__ w1p) {
    const int t  = blockIdx.x * 256 + threadIdx.x;   // 0..8191
    const int cg = t >> 5;            // global channel 0..255
    const int k0 = (t & 31) << 3;     // 0..248, 8 k per thread
    const int nh = cg >> 7;
    const int cl = cg & 127;
    const int kk = k0 >> 6;
    const int kl = k0 & 63;
    const float* wp = W1 + (size_t)cg * CDIM + k0;
    const float4 u = *reinterpret_cast<const float4*>(wp);
    const float4 v = *reinterpret_cast<const float4*>(wp + 4);
    bf16x8 w;
    w[0] = (short)f2bf(u.x); w[1] = (short)f2bf(u.y);
    w[2] = (short)f2bf(u.z); w[3] = (short)f2bf(u.w);
    w[4] = (short)f2bf(v.x); w[5] = (short)f2bf(v.y);
    w[6] = (short)f2bf(v.z); w[7] = (short)f2bf(v.w);
    *reinterpret_cast<bf16x8*>(
        w1p + (size_t)(nh * 4 + kk) * 16384 + tswz(cl, kl * 2)) = w;
}

// F2t[px][c] = sum_k W1[c,k] * feat[k][px]  (FP8 E4M3, channel-last).
// R21 champion (71.6us), byte-identical: 2 m-tiles/block, B fully LDS-resident
// via global_load_lds from pre-swizzled W1_prep; depth-2 A reg prefetch; XCD
// map xcd=b&7 -> image xcd's f2t written entirely by XCD xcd (R22 exploits
// this in point_kernel); fp8 epilogue; (256,2).
__global__ __launch_bounds__(256, 2) void f2_gemm(
    const float* __restrict__ feat, const char* __restrict__ w1p,
    unsigned char* __restrict__ f2t) {
    __shared__ __attribute__((aligned(16))) char ldsc[81920];  // A 16KB + B 64KB

    const int t      = threadIdx.x;
    const int b      = blockIdx.x;                  // 0..1023
    const int xcd    = b & 7;
    const int n_half = (b >> 3) & 1;
    const int jj     = b >> 4;                      // 0..63
    const int mt0    = xcd * 128 + jj * 2;          // tile0; tile1 = +1
    const int m_base0 = mt0 << 7;
    const float* fb[2];
    fb[0] = feat + (size_t)(m_base0 >> 14) * (CDIM * HW) + (m_base0 & (HW - 1));
    fb[1] = fb[0] + 128;                            // same image, +128 px

    const int lane = t & 63;
    const int wid  = t >> 6;
    const int wm   = wid >> 1;           // 2 px-slabs of 64
    const int wn   = wid & 1;            // 2 c-slabs of 64
    const int rr   = lane & 15;
    const int kg   = lane >> 4;

    const int sm0 = (t >> 3) << 2;       // A staging row base 0..124
    const int kb  = (t & 7) << 3;        // A staging k base 0..56

    f32x4 acc[4][4] = {};                // [mi(px)][ni(c)] -> D[c][px]
    float av[2][8][4];                   // A raw, double reg buffer

    auto load_a = [&](const float* fbase, int kk, int rb) {
        const float* fk = fbase + (size_t)(kk * 64 + kb) * HW + sm0;
#pragma unroll
        for (int dk = 0; dk < 8; ++dk) {
            const float4 v = *reinterpret_cast<const float4*>(fk + (size_t)dk * HW);
            av[rb][dk][0] = v.x; av[rb][dk][1] = v.y;
            av[rb][dk][2] = v.z; av[rb][dk][3] = v.w;
        }
    };

    auto write_a = [&](int rb) {
#pragma unroll
        for (int dm = 0; dm < 4; ++dm) {           // transpose in regs
            const int row = sm0 + dm;
            bf16x8 w;
#pragma unroll
            for (int dk = 0; dk < 8; ++dk) w[dk] = (short)f2bf(av[rb][dk][dm]);
            *reinterpret_cast<bf16x8*>(ldsc + tswz(row, kb * 2)) = w;
        }
    };

    auto compute = [&](int kk) {
        const char* bbase = ldsc + BOFF + kk * 16384;
#pragma unroll
        for (int ks = 0; ks < 2; ++ks) {
            const int kb2 = ks * 64 + (kg << 4);
            bf16x8 af[4], bfr[4];
#pragma unroll
            for (int mi = 0; mi < 4; ++mi) {
                const int row = wm * 64 + mi * 16 + rr;
                af[mi] = *reinterpret_cast<const bf16x8*>(ldsc + tswz(row, kb2));
            }
#pragma unroll
            for (int ni = 0; ni < 4; ++ni) {
                const int c = wn * 64 + ni * 16 + rr;
                bfr[ni] = *reinterpret_cast<const bf16x8*>(bbase + tswz(c, kb2));
            }
#pragma unroll
            for (int mi = 0; mi < 4; ++mi)
#pragma unroll
                for (int ni = 0; ni < 4; ++ni)
                    acc[mi][ni] = __builtin_amdgcn_mfma_f32_16x16x32_bf16(
                        bfr[ni], af[mi], acc[mi][ni], 0, 0, 0);   // D[c][px]
        }
    };

    auto store_acc = [&](int tile) {     // fp8 pack -> 4B stores; then rezero
        const int mb = m_base0 + tile * 128;
#pragma unroll
        for (int mi = 0; mi < 4; ++mi) {
            const int px = mb + wm * 64 + mi * 16 + rr;
#pragma unroll
            for (int ni = 0; ni < 4; ++ni) {
                const int c0 = n_half * 128 + wn * 64 + ni * 16 + kg * 4;
                int p = __builtin_amdgcn_cvt_pk_fp8_f32(
                    acc[mi][ni][0], acc[mi][ni][1], 0, false);
                p = __builtin_amdgcn_cvt_pk_fp8_f32(
                    acc[mi][ni][2], acc[mi][ni][3], p, true);
                *reinterpret_cast<unsigned*>(f2t + (size_t)px * CDIM + c0) = (unsigned)p;
                acc[mi][ni] = f32x4{0.f, 0.f, 0.f, 0.f};
            }
        }
    };

    // ---- prologue: ALL 4 B-chunks -> LDS once; A(0),A(1) of tile0 in regs
    {
        const char* src = w1p + (size_t)n_half * 65536 + wid * 4096 + (lane << 4);
        char* dst = ldsc + BOFF + wid * 4096;      // wave-uniform base
#pragma unroll
        for (int kk = 0; kk < 4; ++kk)
#pragma unroll
            for (int i = 0; i < 4; ++i)
                __builtin_amdgcn_global_load_lds(
                    (const void*)(src + kk * 16384 + i * 1024),
                    (void*)(dst + kk * 16384 + i * 1024), 16, 0, 0);
    }
    load_a(fb[0], 0, 0);
    load_a(fb[0], 1, 1);
    write_a(0);
    __syncthreads();   // drains glds B chunks + orders A write

    // ---- main: 8 steps = 2 tiles x 4 K-chunks; only A staged per step ----
#pragma unroll
    for (int tile = 0; tile < 2; ++tile) {
#pragma unroll
        for (int kk = 0; kk < 4; ++kk) {
            const int s = tile * 4 + kk;
            if (s + 2 < 8)                        // depth-2 A prefetch
                load_a(fb[(s + 2) >> 2], (s + 2) & 3, (s + 2) & 1);
            compute(kk);
            if (kk == 3) store_acc(tile);         // mid/final epilogue
            __syncthreads();
            if (s < 7) { write_a((s + 1) & 1); __syncthreads(); }
        }
    }
}

// 2 sample points per wave, XCD-LOCAL image mapping (R22 single change):
// block b handles image b&7; with round-robin dispatch (b%8 -> XCD, same
// assumption R9 validated), every gather targets the 4MB f2t window that
// THE SAME XCD just wrote in f2_gemm (xcd=b&7 there) -> L2-local instead
// of cross-die L3. local = (b>>3)*8 + widx*2 + half is bijective in [0,8192).
__global__ __launch_bounds__(256) void point_kernel(
    const unsigned char* __restrict__ f2t,
    const float* __restrict__ be,
    const float* __restrict__ b1, const float* __restrict__ W2,
    float* __restrict__ out) {
    const int b    = blockIdx.x;                    // 0..8191
    const int lane = threadIdx.x & 63;
    const int widx = (threadIdx.x >> 6) & 3;
    const int img  = b & 7;
    const int local = ((b >> 3) << 3) | (widx << 1) | (lane >> 5);  // 0..8191
    const int p    = img * 8192 + local;            // 0..65535
    const int l5   = lane & 31;
    const int c0   = l5 << 3;

    const float ex = be[p * 2 + 0];
    const float ey = be[p * 2 + 1];
    const float gx = ex * (2.0f / 128.0f) - 1.0f;
    const float gy = ey * (2.0f / 128.0f) - 1.0f;
    const float px = (gx + 1.0f) * 64.0f - 0.5f;
    const float py = (gy + 1.0f) * 64.0f - 0.5f;
    const float x0f = floorf(px), y0f = floorf(py);
    const int   x0 = (int)x0f, y0 = (int)y0f;
    const float wx1 = px - x0f, wy1 = py - y0f;
    const float wx0 = 1.0f - wx1, wy0 = 1.0f - wy1;

    const size_t pix_base = (size_t)img * HW;

    float s[8] = {};
#pragma unroll
    for (int cy = 0; cy < 2; ++cy) {
        const int   yi  = y0 + cy;
        const float wy  = cy ? wy1 : wy0;
        const bool  yin = (yi >= 0) && (yi < 128);
        const int   yc  = min(max(yi, 0), 127);
#pragma unroll
        for (int cx = 0; cx < 2; ++cx) {
            const int   xi  = x0 + cx;
            const float wx  = cx ? wx1 : wx0;
            const bool  xin = (xi >= 0) && (xi < 128);
            const int   xc  = min(max(xi, 0), 127);
            const float w   = wx * wy * (float)(xin && yin);
            const uint2 v = *reinterpret_cast<const uint2*>(
                &f2t[(pix_base + (size_t)yc * 128 + xc) * 256 + c0]);
            const f32x2 f01 = __builtin_amdgcn_cvt_pk_f32_fp8((int)v.x, false);
            const f32x2 f23 = __builtin_amdgcn_cvt_pk_f32_fp8((int)v.x, true);
            const f32x2 f45 = __builtin_amdgcn_cvt_pk_f32_fp8((int)v.y, false);
            const f32x2 f67 = __builtin_amdgcn_cvt_pk_f32_fp8((int)v.y, true);
            s[0] += w * f01[0]; s[1] += w * f01[1];
            s[2] += w * f23[0]; s[3] += w * f23[1];
            s[4] += w * f45[0]; s[5] += w * f45[1];
            s[6] += w * f67[0]; s[7] += w * f67[1];
        }
    }
    const float4 bb0 = *reinterpret_cast<const float4*>(&b1[c0]);
    const float4 bb1 = *reinterpret_cast<const float4*>(&b1[c0 + 4]);
    const float4 wa0 = *reinterpret_cast<const float4*>(&W2[c0]);
    const float4 wa1 = *reinterpret_cast<const float4*>(&W2[c0 + 4]);
    const float4 wb0 = *reinterpret_cast<const float4*>(&W2[256 + c0]);
    const float4 wb1 = *reinterpret_cast<const float4*>(&W2[256 + c0 + 4]);
    float bias[8] = {bb0.x, bb0.y, bb0.z, bb0.w, bb1.x, bb1.y, bb1.z, bb1.w};
    float w2a[8]  = {wa0.x, wa0.y, wa0.z, wa0.w, wa1.x, wa1.y, wa1.z, wa1.w};
    float w2b[8]  = {wb0.x, wb0.y, wb0.z, wb0.w, wb1.x, wb1.y, wb1.z, wb1.w};

    float a0 = 0.f, a1 = 0.f;
#pragma unroll
    for (int j = 0; j < 8; ++j) {
        const float h = fmaxf(s[j] + bias[j], 0.f);
        a0 += h * w2a[j];
        a1 += h * w2b[j];
    }
#pragma unroll
    for (int off = 16; off > 0; off >>= 1) {
        a0 += __shfl_xor(a0, off);
        a1 += __shfl_xor(a1, off);
    }
    if (l5 == 0) {
        out[p * 2 + 0] = ex + a0;
        out[p * 2 + 1] = ey + a1;
    }
}

extern "C" void kernel_launch(void* const* d_in, const int* in_sizes, int n_in,
                              void* d_out, int out_size, void* d_ws, size_t ws_size,
                              hipStream_t stream) {
    const float* feat = (const float*)d_in[0];
    const float* be   = (const float*)d_in[1];
    const float* W1   = (const float*)d_in[2];
    const float* b1   = (const float*)d_in[3];
    const float* W2   = (const float*)d_in[4];
    float* out = (float*)d_out;
    unsigned char* f2t = (unsigned char*)d_ws;              // 32 MiB fp8
    char* w1p = (char*)d_ws + (33554432);                   // 128 KiB prep

    w1_prep<<<32, 256, 0, stream>>>(W1, w1p);
    f2_gemm<<<1024, 256, 0, stream>>>(feat, w1p, f2t);
    point_kernel<<<8192, 256, 0, stream>>>(f2t, be, b1, W2, out);
}

// Round 23
// 69.887 us; speedup vs baseline: 1.0680x; 1.0170x over previous
//
#include <hip/hip_runtime.h>
#include <hip/hip_bf16.h>

typedef __attribute__((ext_vector_type(4))) float f32x4;
typedef __attribute__((ext_vector_type(2))) float f32x2;
typedef __attribute__((ext_vector_type(8))) short bf16x8;

#define HW    16384   // 128*128
#define CDIM  256
#define BOFF  16384   // B region base in LDS (A: [0,16384)); B: 4 x 16KB chunks

__device__ __forceinline__ unsigned short f2bf(float x) {
    union { float f; unsigned u; } c; c.f = x;
    unsigned r = c.u + 0x7fffu + ((c.u >> 16) & 1u);   // RNE
    return (unsigned short)(r >> 16);
}

// Tile layout (R2-proven): rows of 64 k bf16 = 128 B,
// byte(row,k) = row*128 + ((k*2) ^ ((row&7)<<4)).
__device__ __forceinline__ int tswz(int row, int kbyte) {
    return row * 128 + (kbyte ^ ((row & 7) << 4));
}

// Prep: write W1 as 8 x 16KB chunks, each the exact byte image of one
// (n_half, kk) B-tile in LDS (bf16 + tswz). 8192 threads, 8 k each.
__global__ __launch_bounds__(256) void w1_prep(
    const float* __restrict__ W1, char* __restrict__ w1p) {
    const int t  = blockIdx.x * 256 + threadIdx.x;   // 0..8191
    const int cg = t >> 5;            // global channel 0..255
    const int k0 = (t & 31) << 3;     // 0..248, 8 k per thread
    const int nh = cg >> 7;
    const int cl = cg & 127;
    const int kk = k0 >> 6;
    const int kl = k0 & 63;
    const float* wp = W1 + (size_t)cg * CDIM + k0;
    const float4 u = *reinterpret_cast<const float4*>(wp);
    const float4 v = *reinterpret_cast<const float4*>(wp + 4);
    bf16x8 w;
    w[0] = (short)f2bf(u.x); w[1] = (short)f2bf(u.y);
    w[2] = (short)f2bf(u.z); w[3] = (short)f2bf(u.w);
    w[4] = (short)f2bf(v.x); w[5] = (short)f2bf(v.y);
    w[6] = (short)f2bf(v.z); w[7] = (short)f2bf(v.w);
    *reinterpret_cast<bf16x8*>(
        w1p + (size_t)(nh * 4 + kk) * 16384 + tswz(cl, kl * 2)) = w;
}

// F2t[px][c] = sum_k W1[c,k] * feat[k][px]  (FP8 E4M3, channel-last).
// R21/R22 champion + FOUR m-tiles per block (grid 512 -> ONE generation:
// 512 blocks = 256 CU x 2 resident; every prologue runs concurrently once,
// then pure streaming -- R21's generation-amortization pushed to its limit).
// Per XCD: 128 m-tiles = exactly one image, so fb[tile]=fb[0]+tile*128 never
// crosses an image. Everything else byte-identical: B fully LDS-resident via
// global_load_lds from pre-swizzled W1_prep (R20 +1.3us), depth-2 A reg
// prefetch wrapping across tiles (R12 -4us), tswz, fp8 epilogue per tile,
// XCD map (R9 -8us), (256,2) (arg>=3 spills R6/R10).
__global__ __launch_bounds__(256, 2) void f2_gemm(
    const float* __restrict__ feat, const char* __restrict__ w1p,
    unsigned char* __restrict__ f2t) {
    __shared__ __attribute__((aligned(16))) char ldsc[81920];  // A 16KB + B 64KB

    const int t      = threadIdx.x;
    const int b      = blockIdx.x;                  // 0..511
    const int xcd    = b & 7;
    const int n_half = (b >> 3) & 1;
    const int jj     = b >> 4;                      // 0..31
    const int mt0    = xcd * 128 + jj * 4;          // tiles mt0..mt0+3
    const int m_base0 = mt0 << 7;
    const float* fb0 = feat + (size_t)(m_base0 >> 14) * (CDIM * HW) + (m_base0 & (HW - 1));

    const int lane = t & 63;
    const int wid  = t >> 6;
    const int wm   = wid >> 1;           // 2 px-slabs of 64
    const int wn   = wid & 1;            // 2 c-slabs of 64
    const int rr   = lane & 15;
    const int kg   = lane >> 4;

    const int sm0 = (t >> 3) << 2;       // A staging row base 0..124
    const int kb  = (t & 7) << 3;        // A staging k base 0..56

    f32x4 acc[4][4] = {};                // [mi(px)][ni(c)] -> D[c][px]
    float av[2][8][4];                   // A raw, double reg buffer

    // global step s = tile*4 + kk, tile 0..3, kk 0..3
    auto load_a = [&](int s, int rb) {
        const float* fk = fb0 + (s >> 2) * 128
                        + (size_t)((s & 3) * 64 + kb) * HW + sm0;
#pragma unroll
        for (int dk = 0; dk < 8; ++dk) {
            const float4 v = *reinterpret_cast<const float4*>(fk + (size_t)dk * HW);
            av[rb][dk][0] = v.x; av[rb][dk][1] = v.y;
            av[rb][dk][2] = v.z; av[rb][dk][3] = v.w;
        }
    };

    auto write_a = [&](int rb) {
#pragma unroll
        for (int dm = 0; dm < 4; ++dm) {           // transpose in regs
            const int row = sm0 + dm;
            bf16x8 w;
#pragma unroll
            for (int dk = 0; dk < 8; ++dk) w[dk] = (short)f2bf(av[rb][dk][dm]);
            *reinterpret_cast<bf16x8*>(ldsc + tswz(row, kb * 2)) = w;
        }
    };

    auto compute = [&](int kk) {
        const char* bbase = ldsc + BOFF + kk * 16384;
#pragma unroll
        for (int ks = 0; ks < 2; ++ks) {
            const int kb2 = ks * 64 + (kg << 4);
            bf16x8 af[4], bfr[4];
#pragma unroll
            for (int mi = 0; mi < 4; ++mi) {
                const int row = wm * 64 + mi * 16 + rr;
                af[mi] = *reinterpret_cast<const bf16x8*>(ldsc + tswz(row, kb2));
            }
#pragma unroll
            for (int ni = 0; ni < 4; ++ni) {
                const int c = wn * 64 + ni * 16 + rr;
                bfr[ni] = *reinterpret_cast<const bf16x8*>(bbase + tswz(c, kb2));
            }
#pragma unroll
            for (int mi = 0; mi < 4; ++mi)
#pragma unroll
                for (int ni = 0; ni < 4; ++ni)
                    acc[mi][ni] = __builtin_amdgcn_mfma_f32_16x16x32_bf16(
                        bfr[ni], af[mi], acc[mi][ni], 0, 0, 0);   // D[c][px]
        }
    };

    auto store_acc = [&](int tile) {     // fp8 pack -> 4B stores; then rezero
        const int mb = m_base0 + tile * 128;
#pragma unroll
        for (int mi = 0; mi < 4; ++mi) {
            const int px = mb + wm * 64 + mi * 16 + rr;
#pragma unroll
            for (int ni = 0; ni < 4; ++ni) {
                const int c0 = n_half * 128 + wn * 64 + ni * 16 + kg * 4;
                int p = __builtin_amdgcn_cvt_pk_fp8_f32(
                    acc[mi][ni][0], acc[mi][ni][1], 0, false);
                p = __builtin_amdgcn_cvt_pk_fp8_f32(
                    acc[mi][ni][2], acc[mi][ni][3], p, true);
                *reinterpret_cast<unsigned*>(f2t + (size_t)px * CDIM + c0) = (unsigned)p;
                acc[mi][ni] = f32x4{0.f, 0.f, 0.f, 0.f};
            }
        }
    };

    // ---- prologue: ALL 4 B-chunks -> LDS once; A(0),A(1) in regs ----
    {
        const char* src = w1p + (size_t)n_half * 65536 + wid * 4096 + (lane << 4);
        char* dst = ldsc + BOFF + wid * 4096;      // wave-uniform base
#pragma unroll
        for (int kk = 0; kk < 4; ++kk)
#pragma unroll
            for (int i = 0; i < 4; ++i)
                __builtin_amdgcn_global_load_lds(
                    (const void*)(src + kk * 16384 + i * 1024),
                    (void*)(dst + kk * 16384 + i * 1024), 16, 0, 0);
    }
    load_a(0, 0);
    load_a(1, 1);
    write_a(0);
    __syncthreads();   // drains glds B chunks + orders A write

    // ---- main: 16 steps = 4 tiles x 4 K-chunks; only A staged per step ----
#pragma unroll
    for (int tile = 0; tile < 4; ++tile) {
#pragma unroll
        for (int kk = 0; kk < 4; ++kk) {
            const int s = tile * 4 + kk;
            if (s + 2 < 16)                       // depth-2 A prefetch
                load_a(s + 2, s & 1);
            compute(kk);
            if (kk == 3) store_acc(tile);         // per-tile fp8 epilogue
            __syncthreads();
            if (s < 15) { write_a((s + 1) & 1); __syncthreads(); }
        }
    }
}

// 2 sample points per wave, XCD-LOCAL image mapping (R22, kept): block b
// handles image b&7 -> gathers hit the 4MB f2t window its own XCD wrote.
__global__ __launch_bounds__(256) void point_kernel(
    const unsigned char* __restrict__ f2t,
    const float* __restrict__ be,
    const float* __restrict__ b1, const float* __restrict__ W2,
    float* __restrict__ out) {
    const int b    = blockIdx.x;                    // 0..8191
    const int lane = threadIdx.x & 63;
    const int widx = (threadIdx.x >> 6) & 3;
    const int img  = b & 7;
    const int local = ((b >> 3) << 3) | (widx << 1) | (lane >> 5);  // 0..8191
    const int p    = img * 8192 + local;            // 0..65535
    const int l5   = lane & 31;
    const int c0   = l5 << 3;

    const float ex = be[p * 2 + 0];
    const float ey = be[p * 2 + 1];
    const float gx = ex * (2.0f / 128.0f) - 1.0f;
    const float gy = ey * (2.0f / 128.0f) - 1.0f;
    const float px = (gx + 1.0f) * 64.0f - 0.5f;
    const float py = (gy + 1.0f) * 64.0f - 0.5f;
    const float x0f = floorf(px), y0f = floorf(py);
    const int   x0 = (int)x0f, y0 = (int)y0f;
    const float wx1 = px - x0f, wy1 = py - y0f;
    const float wx0 = 1.0f - wx1, wy0 = 1.0f - wy1;

    const size_t pix_base = (size_t)img * HW;

    float s[8] = {};
#pragma unroll
    for (int cy = 0; cy < 2; ++cy) {
        const int   yi  = y0 + cy;
        const float wy  = cy ? wy1 : wy0;
        const bool  yin = (yi >= 0) && (yi < 128);
        const int   yc  = min(max(yi, 0), 127);
#pragma unroll
        for (int cx = 0; cx < 2; ++cx) {
            const int   xi  = x0 + cx;
            const float wx  = cx ? wx1 : wx0;
            const bool  xin = (xi >= 0) && (xi < 128);
            const int   xc  = min(max(xi, 0), 127);
            const float w   = wx * wy * (float)(xin && yin);
            const uint2 v = *reinterpret_cast<const uint2*>(
                &f2t[(pix_base + (size_t)yc * 128 + xc) * 256 + c0]);
            const f32x2 f01 = __builtin_amdgcn_cvt_pk_f32_fp8((int)v.x, false);
            const f32x2 f23 = __builtin_amdgcn_cvt_pk_f32_fp8((int)v.x, true);
            const f32x2 f45 = __builtin_amdgcn_cvt_pk_f32_fp8((int)v.y, false);
            const f32x2 f67 = __builtin_amdgcn_cvt_pk_f32_fp8((int)v.y, true);
            s[0] += w * f01[0]; s[1] += w * f01[1];
            s[2] += w * f23[0]; s[3] += w * f23[1];
            s[4] += w * f45[0]; s[5] += w * f45[1];
            s[6] += w * f67[0]; s[7] += w * f67[1];
        }
    }
    const float4 bb0 = *reinterpret_cast<const float4*>(&b1[c0]);
    const float4 bb1 = *reinterpret_cast<const float4*>(&b1[c0 + 4]);
    const float4 wa0 = *reinterpret_cast<const float4*>(&W2[c0]);
    const float4 wa1 = *reinterpret_cast<const float4*>(&W2[c0 + 4]);
    const float4 wb0 = *reinterpret_cast<const float4*>(&W2[256 + c0]);
    const float4 wb1 = *reinterpret_cast<const float4*>(&W2[256 + c0 + 4]);
    float bias[8] = {bb0.x, bb0.y, bb0.z, bb0.w, bb1.x, bb1.y, bb1.z, bb1.w};
    float w2a[8]  = {wa0.x, wa0.y, wa0.z, wa0.w, wa1.x, wa1.y, wa1.z, wa1.w};
    float w2b[8]  = {wb0.x, wb0.y, wb0.z, wb0.w, wb1.x, wb1.y, wb1.z, wb1.w};

    float a0 = 0.f, a1 = 0.f;
#pragma unroll
    for (int j = 0; j < 8; ++j) {
        const float h = fmaxf(s[j] + bias[j], 0.f);
        a0 += h * w2a[j];
        a1 += h * w2b[j];
    }
#pragma unroll
    for (int off = 16; off > 0; off >>= 1) {
        a0 += __shfl_xor(a0, off);
        a1 += __shfl_xor(a1, off);
    }
    if (l5 == 0) {
        out[p * 2 + 0] = ex + a0;
        out[p * 2 + 1] = ey + a1;
    }
}

extern "C" void kernel_launch(void* const* d_in, const int* in_sizes, int n_in,
                              void* d_out, int out_size, void* d_ws, size_t ws_size,
                              hipStream_t stream) {
    const float* feat = (const float*)d_in[0];
    const float* be   = (const float*)d_in[1];
    const float* W1   = (const float*)d_in[2];
    const float* b1   = (const float*)d_in[3];
    const float* W2   = (const float*)d_in[4];
    float* out = (float*)d_out;
    unsigned char* f2t = (unsigned char*)d_ws;              // 32 MiB fp8
    char* w1p = (char*)d_ws + (33554432);                   // 128 KiB prep

    w1_prep<<<32, 256, 0, stream>>>(W1, w1p);
    f2_gemm<<<512, 256, 0, stream>>>(feat, w1p, f2t);
    point_kernel<<<8192, 256, 0, stream>>>(f2t, be, b1, W2, out);
}

// Round 24
// 61.376 us; speedup vs baseline: 1.2161x; 1.1387x over previous
//
#include <hip/hip_runtime.h>
#include <hip/hip_bf16.h>

typedef __attribute__((ext_vector_type(4))) float f32x4;
typedef __attribute__((ext_vector_type(2))) float f32x2;
typedef __attribute__((ext_vector_type(8))) short bf16x8;

#define HW    16384   // 128*128
#define CDIM  256
#define BOFF  16384   // B region base in LDS (A: [0,16384)); B: 4 x 16KB chunks

__device__ __forceinline__ unsigned short f2bf(float x) {
    union { float f; unsigned u; } c; c.f = x;
    unsigned r = c.u + 0x7fffu + ((c.u >> 16) & 1u);   // RNE
    return (unsigned short)(r >> 16);
}

// Tile layout (R2-proven): rows of 64 k bf16 = 128 B,
// byte(row,k) = row*128 + ((k*2) ^ ((row&7)<<4)).
__device__ __forceinline__ int tswz(int row, int kbyte) {
    return row * 128 + (kbyte ^ ((row & 7) << 4));
}

// Prep: write W1 as 8 x 16KB chunks, each the exact byte image of one
// (n_half, kk) B-tile in LDS (bf16 + tswz). 8192 threads, 8 k each.
__global__ __launch_bounds__(256) void w1_prep(
    const float* __restrict__ W1, char* __restrict__ w1p) {
    const int t  = blockIdx.x * 256 + threadIdx.x;   // 0..8191
    const int cg = t >> 5;            // global channel 0..255
    const int k0 = (t & 31) << 3;     // 0..248, 8 k per thread
    const int nh = cg >> 7;
    const int cl = cg & 127;
    const int kk = k0 >> 6;
    const int kl = k0 & 63;
    const float* wp = W1 + (size_t)cg * CDIM + k0;
    const float4 u = *reinterpret_cast<const float4*>(wp);
    const float4 v = *reinterpret_cast<const float4*>(wp + 4);
    bf16x8 w;
    w[0] = (short)f2bf(u.x); w[1] = (short)f2bf(u.y);
    w[2] = (short)f2bf(u.z); w[3] = (short)f2bf(u.w);
    w[4] = (short)f2bf(v.x); w[5] = (short)f2bf(v.y);
    w[6] = (short)f2bf(v.z); w[7] = (short)f2bf(v.w);
    *reinterpret_cast<bf16x8*>(
        w1p + (size_t)(nh * 4 + kk) * 16384 + tswz(cl, kl * 2)) = w;
}

// F2t[px][c] = sum_k W1[c,k] * feat[k][px]  (FP8 E4M3, channel-last).
// R23 champion (69.9us) with ONE change: A-staging thread map swapped so
// each global-load instruction covers 2 x 512B contiguous segments instead
// of 8 x 128B (sm0=(t&31)*4, kb=(t>>5)*8; lanes 0..31 = one k-row of 128 px).
// 4x longer DRAM/L2 segments, same instruction count; per-thread k stays a
// contiguous octet so write_a/tswz/compute are byte-identical. Write-side
// bank cost rises ~4-way (4 ops/thread, negligible). All proven pieces kept:
// 4 m-tiles/block one-generation grid 512 (R23 -1.2us), B fully LDS-resident
// via global_load_lds from pre-swizzled W1_prep (R20/R21 -4.3us), depth-2 A
// reg prefetch (R12 -4us), XCD map (R9 -8us), fp8 f2t (R18), (256,2).
__global__ __launch_bounds__(256, 2) void f2_gemm(
    const float* __restrict__ feat, const char* __restrict__ w1p,
    unsigned char* __restrict__ f2t) {
    __shared__ __attribute__((aligned(16))) char ldsc[81920];  // A 16KB + B 64KB

    const int t      = threadIdx.x;
    const int b      = blockIdx.x;                  // 0..511
    const int xcd    = b & 7;
    const int n_half = (b >> 3) & 1;
    const int jj     = b >> 4;                      // 0..31
    const int mt0    = xcd * 128 + jj * 4;          // tiles mt0..mt0+3
    const int m_base0 = mt0 << 7;
    const float* fb0 = feat + (size_t)(m_base0 >> 14) * (CDIM * HW) + (m_base0 & (HW - 1));

    const int lane = t & 63;
    const int wid  = t >> 6;
    const int wm   = wid >> 1;           // 2 px-slabs of 64
    const int wn   = wid & 1;            // 2 c-slabs of 64
    const int rr   = lane & 15;
    const int kg   = lane >> 4;

    // A staging map (R24 change): lanes 0..31 cover all 128 px of ONE k-row
    const int sm0 = (t & 31) << 2;       // px quad base 0..124
    const int kb  = (t >> 5) << 3;       // k octet base 0..56

    f32x4 acc[4][4] = {};                // [mi(px)][ni(c)] -> D[c][px]
    float av[2][8][4];                   // A raw, double reg buffer

    // global step s = tile*4 + kk, tile 0..3, kk 0..3
    auto load_a = [&](int s, int rb) {
        const float* fk = fb0 + (s >> 2) * 128
                        + (size_t)((s & 3) * 64 + kb) * HW + sm0;
#pragma unroll
        for (int dk = 0; dk < 8; ++dk) {
            const float4 v = *reinterpret_cast<const float4*>(fk + (size_t)dk * HW);
            av[rb][dk][0] = v.x; av[rb][dk][1] = v.y;
            av[rb][dk][2] = v.z; av[rb][dk][3] = v.w;
        }
    };

    auto write_a = [&](int rb) {
#pragma unroll
        for (int dm = 0; dm < 4; ++dm) {           // transpose in regs
            const int row = sm0 + dm;
            bf16x8 w;
#pragma unroll
            for (int dk = 0; dk < 8; ++dk) w[dk] = (short)f2bf(av[rb][dk][dm]);
            *reinterpret_cast<bf16x8*>(ldsc + tswz(row, kb * 2)) = w;
        }
    };

    auto compute = [&](int kk) {
        const char* bbase = ldsc + BOFF + kk * 16384;
#pragma unroll
        for (int ks = 0; ks < 2; ++ks) {
            const int kb2 = ks * 64 + (kg << 4);
            bf16x8 af[4], bfr[4];
#pragma unroll
            for (int mi = 0; mi < 4; ++mi) {
                const int row = wm * 64 + mi * 16 + rr;
                af[mi] = *reinterpret_cast<const bf16x8*>(ldsc + tswz(row, kb2));
            }
#pragma unroll
            for (int ni = 0; ni < 4; ++ni) {
                const int c = wn * 64 + ni * 16 + rr;
                bfr[ni] = *reinterpret_cast<const bf16x8*>(bbase + tswz(c, kb2));
            }
#pragma unroll
            for (int mi = 0; mi < 4; ++mi)
#pragma unroll
                for (int ni = 0; ni < 4; ++ni)
                    acc[mi][ni] = __builtin_amdgcn_mfma_f32_16x16x32_bf16(
                        bfr[ni], af[mi], acc[mi][ni], 0, 0, 0);   // D[c][px]
        }
    };

    auto store_acc = [&](int tile) {     // fp8 pack -> 4B stores; then rezero
        const int mb = m_base0 + tile * 128;
#pragma unroll
        for (int mi = 0; mi < 4; ++mi) {
            const int px = mb + wm * 64 + mi * 16 + rr;
#pragma unroll
            for (int ni = 0; ni < 4; ++ni) {
                const int c0 = n_half * 128 + wn * 64 + ni * 16 + kg * 4;
                int p = __builtin_amdgcn_cvt_pk_fp8_f32(
                    acc[mi][ni][0], acc[mi][ni][1], 0, false);
                p = __builtin_amdgcn_cvt_pk_fp8_f32(
                    acc[mi][ni][2], acc[mi][ni][3], p, true);
                *reinterpret_cast<unsigned*>(f2t + (size_t)px * CDIM + c0) = (unsigned)p;
                acc[mi][ni] = f32x4{0.f, 0.f, 0.f, 0.f};
            }
        }
    };

    // ---- prologue: ALL 4 B-chunks -> LDS once; A(0),A(1) in regs ----
    {
        const char* src = w1p + (size_t)n_half * 65536 + wid * 4096 + (lane << 4);
        char* dst = ldsc + BOFF + wid * 4096;      // wave-uniform base
#pragma unroll
        for (int kk = 0; kk < 4; ++kk)
#pragma unroll
            for (int i = 0; i < 4; ++i)
                __builtin_amdgcn_global_load_lds(
                    (const void*)(src + kk * 16384 + i * 1024),
                    (void*)(dst + kk * 16384 + i * 1024), 16, 0, 0);
    }
    load_a(0, 0);
    load_a(1, 1);
    write_a(0);
    __syncthreads();   // drains glds B chunks + orders A write

    // ---- main: 16 steps = 4 tiles x 4 K-chunks; only A staged per step ----
#pragma unroll
    for (int tile = 0; tile < 4; ++tile) {
#pragma unroll
        for (int kk = 0; kk < 4; ++kk) {
            const int s = tile * 4 + kk;
            if (s + 2 < 16)                       // depth-2 A prefetch
                load_a(s + 2, s & 1);
            compute(kk);
            if (kk == 3) store_acc(tile);         // per-tile fp8 epilogue
            __syncthreads();
            if (s < 15) { write_a((s + 1) & 1); __syncthreads(); }
        }
    }
}

// 2 sample points per wave, XCD-LOCAL image mapping (R22, kept): block b
// handles image b&7 -> gathers hit the 4MB f2t window its own XCD wrote.
__global__ __launch_bounds__(256) void point_kernel(
    const unsigned char* __restrict__ f2t,
    const float* __restrict__ be,
    const float* __restrict__ b1, const float* __restrict__ W2,
    float* __restrict__ out) {
    const int b    = blockIdx.x;                    // 0..8191
    const int lane = threadIdx.x & 63;
    const int widx = (threadIdx.x >> 6) & 3;
    const int img  = b & 7;
    const int local = ((b >> 3) << 3) | (widx << 1) | (lane >> 5);  // 0..8191
    const int p    = img * 8192 + local;            // 0..65535
    const int l5   = lane & 31;
    const int c0   = l5 << 3;

    const float ex = be[p * 2 + 0];
    const float ey = be[p * 2 + 1];
    const float gx = ex * (2.0f / 128.0f) - 1.0f;
    const float gy = ey * (2.0f / 128.0f) - 1.0f;
    const float px = (gx + 1.0f) * 64.0f - 0.5f;
    const float py = (gy + 1.0f) * 64.0f - 0.5f;
    const float x0f = floorf(px), y0f = floorf(py);
    const int   x0 = (int)x0f, y0 = (int)y0f;
    const float wx1 = px - x0f, wy1 = py - y0f;
    const float wx0 = 1.0f - wx1, wy0 = 1.0f - wy1;

    const size_t pix_base = (size_t)img * HW;

    float s[8] = {};
#pragma unroll
    for (int cy = 0; cy < 2; ++cy) {
        const int   yi  = y0 + cy;
        const float wy  = cy ? wy1 : wy0;
        const bool  yin = (yi >= 0) && (yi < 128);
        const int   yc  = min(max(yi, 0), 127);
#pragma unroll
        for (int cx = 0; cx < 2; ++cx) {
            const int   xi  = x0 + cx;
            const float wx  = cx ? wx1 : wx0;
            const bool  xin = (xi >= 0) && (xi < 128);
            const int   xc  = min(max(xi, 0), 127);
            const float w   = wx * wy * (float)(xin && yin);
            const uint2 v = *reinterpret_cast<const uint2*>(
                &f2t[(pix_base + (size_t)yc * 128 + xc) * 256 + c0]);
            const f32x2 f01 = __builtin_amdgcn_cvt_pk_f32_fp8((int)v.x, false);
            const f32x2 f23 = __builtin_amdgcn_cvt_pk_f32_fp8((int)v.x, true);
            const f32x2 f45 = __builtin_amdgcn_cvt_pk_f32_fp8((int)v.y, false);
            const f32x2 f67 = __builtin_amdgcn_cvt_pk_f32_fp8((int)v.y, true);
            s[0] += w * f01[0]; s[1] += w * f01[1];
            s[2] += w * f23[0]; s[3] += w * f23[1];
            s[4] += w * f45[0]; s[5] += w * f45[1];
            s[6] += w * f67[0]; s[7] += w * f67[1];
        }
    }
    const float4 bb0 = *reinterpret_cast<const float4*>(&b1[c0]);
    const float4 bb1 = *reinterpret_cast<const float4*>(&b1[c0 + 4]);
    const float4 wa0 = *reinterpret_cast<const float4*>(&W2[c0]);
    const float4 wa1 = *reinterpret_cast<const float4*>(&W2[c0 + 4]);
    const float4 wb0 = *reinterpret_cast<const float4*>(&W2[256 + c0]);
    const float4 wb1 = *reinterpret_cast<const float4*>(&W2[256 + c0 + 4]);
    float bias[8] = {bb0.x, bb0.y, bb0.z, bb0.w, bb1.x, bb1.y, bb1.z, bb1.w};
    float w2a[8]  = {wa0.x, wa0.y, wa0.z, wa0.w, wa1.x, wa1.y, wa1.z, wa1.w};
    float w2b[8]  = {wb0.x, wb0.y, wb0.z, wb0.w, wb1.x, wb1.y, wb1.z, wb1.w};

    float a0 = 0.f, a1 = 0.f;
#pragma unroll
    for (int j = 0; j < 8; ++j) {
        const float h = fmaxf(s[j] + bias[j], 0.f);
        a0 += h * w2a[j];
        a1 += h * w2b[j];
    }
#pragma unroll
    for (int off = 16; off > 0; off >>= 1) {
        a0 += __shfl_xor(a0, off);
        a1 += __shfl_xor(a1, off);
    }
    if (l5 == 0) {
        out[p * 2 + 0] = ex + a0;
        out[p * 2 + 1] = ey + a1;
    }
}

extern "C" void kernel_launch(void* const* d_in, const int* in_sizes, int n_in,
                              void* d_out, int out_size, void* d_ws, size_t ws_size,
                              hipStream_t stream) {
    const float* feat = (const float*)d_in[0];
    const float* be   = (const float*)d_in[1];
    const float* W1   = (const float*)d_in[2];
    const float* b1   = (const float*)d_in[3];
    const float* W2   = (const float*)d_in[4];
    float* out = (float*)d_out;
    unsigned char* f2t = (unsigned char*)d_ws;              // 32 MiB fp8
    char* w1p = (char*)d_ws + (33554432);                   // 128 KiB prep

    w1_prep<<<32, 256, 0, stream>>>(W1, w1p);
    f2_gemm<<<512, 256, 0, stream>>>(feat, w1p, f2t);
    point_kernel<<<8192, 256, 0, stream>>>(f2t, be, b1, W2, out);
}